// Round 1
// baseline (270.511 us; speedup 1.0000x reference)
//
#include <hip/hip_runtime.h>

#define MUL 16
#define NPAIR 136   // u<=v pairs

// ---------------------------------------------------------------------------
// Preprocessing: fold symmetric pairs + normalization constants into a
// linear weight stream: ws[(p*16 + w)*5 + {f000,f110,f112,f101uv,f101vu}]
// ---------------------------------------------------------------------------
__global__ void prep_weights(const float* __restrict__ w000,
                             const float* __restrict__ w101,
                             const float* __restrict__ w110,
                             const float* __restrict__ w112,
                             float* __restrict__ ws) {
    int idx = blockIdx.x * blockDim.x + threadIdx.x;
    if (idx >= NPAIR * MUL) return;
    int p = idx / MUL, w = idx % MUL;
    // decode p -> (u,v) with u<=v
    int u = 0, rem = p;
    while (rem >= MUL - u) { rem -= MUL - u; ++u; }
    int v = u + rem;

    const float A000 = 0.044194173824159216f;   // sqrt(1/(2*16*16))
    const float A110 = 0.025515518153991442f;   // A000/sqrt(3)
    const float A101 = 0.0625f;                 // sqrt(3/256)/sqrt(3)
    const float A112 = 0.13975424859373686f;    // sqrt(5)/16

    int uv = (u * MUL + v) * MUL + w;
    int vu = (v * MUL + u) * MUL + w;
    float f000, f110, f112, f101uv, f101vu;
    if (u == v) {
        f000   = A000 * w000[uv];
        f110   = A110 * w110[uv];
        f112   = A112 * w112[uv];
        f101uv = A101 * w101[uv];
        f101vu = 0.f;
    } else {
        f000   = A000 * (w000[uv] + w000[vu]);
        f110   = A110 * (w110[uv] + w110[vu]);
        f112   = A112 * (w112[uv] + w112[vu]);
        f101uv = A101 * w101[uv];
        f101vu = A101 * w101[vu];
    }
    float* o = ws + (p * MUL + w) * 5;
    o[0] = f000; o[1] = f110; o[2] = f112; o[3] = f101uv; o[4] = f101vu;
}

// ---------------------------------------------------------------------------
// Main kernel: one thread per node. x staged through LDS (stride 65 floats
// -> 2 lanes/bank, conflict-free). 144 fp32 accumulators in VGPRs; weights
// read wave-uniformly from the folded stream.
// ---------------------------------------------------------------------------
__launch_bounds__(256, 2)
__global__ void tsq_kernel(const float* __restrict__ feats,
                           const float* __restrict__ msgs,
                           const float* __restrict__ wstream,
                           float* __restrict__ out) {
    __shared__ float xsh[256 * 65];
    const int tid = threadIdx.x;
    const long long blockNode = (long long)blockIdx.x * 256;

    // coalesced staging: 256 nodes * 64 floats, float4 loads
    const float4* f4 = (const float4*)(feats + blockNode * 64);
    const float4* m4 = (const float4*)(msgs + blockNode * 64);
#pragma unroll
    for (int r = 0; r < 16; ++r) {
        int i = r * 256 + tid;          // float4 index within block
        float4 a = f4[i];
        float4 b = m4[i];
        int fi   = i * 4;               // float offset within block
        int node = fi >> 6;
        int off  = fi & 63;
        float* dst = &xsh[node * 65 + off];
        dst[0] = a.x + b.x; dst[1] = a.y + b.y;
        dst[2] = a.z + b.z; dst[3] = a.w + b.w;
    }
    __syncthreads();

    float acc0[16];
    float acc1[16][3];
    float acc2[16][5];
#pragma unroll
    for (int w = 0; w < 16; ++w) {
        acc0[w] = 0.f;
#pragma unroll
        for (int k = 0; k < 3; ++k) acc1[w][k] = 0.f;
#pragma unroll
        for (int k = 0; k < 5; ++k) acc2[w][k] = 0.f;
    }

    const float* row = &xsh[tid * 65];
    const float C1 = 0.31622776601683794f;  // 1/sqrt(10)
    const float C2 = 0.18257418583505536f;  // 1/sqrt(30)

    const float* wp = wstream;
    for (int u = 0; u < 16; ++u) {
        float xu0  = row[u];
        float xu1a = row[16 + 3 * u];
        float xu1b = row[16 + 3 * u + 1];
        float xu1c = row[16 + 3 * u + 2];
        for (int v = u; v < 16; ++v) {
            float xv0  = row[v];
            float xv1a = row[16 + 3 * v];
            float xv1b = row[16 + 3 * v + 1];
            float xv1c = row[16 + 3 * v + 2];
            float o00 = xu1a * xv1a, o01 = xu1a * xv1b, o02 = xu1a * xv1c;
            float o10 = xu1b * xv1a, o11 = xu1b * xv1b, o12 = xu1b * xv1c;
            float o20 = xu1c * xv1a, o21 = xu1c * xv1b, o22 = xu1c * xv1c;
            float s0p = xu0 * xv0;
            float s1p = o00 + o11 + o22;
            float t0 = C1 * (o01 + o10);
            float t1 = C1 * (o02 + o20);
            float t2 = C1 * (o12 + o21);
            float t3 = C1 * (o00 - o11);
            float t4 = C2 * (o22 + o22 - o00 - o11);
            float p0 = xu1a * xv0, p1 = xu1b * xv0, p2 = xu1c * xv0;
            float q0 = xv1a * xu0, q1 = xv1b * xu0, q2 = xv1c * xu0;
#pragma unroll
            for (int w = 0; w < 16; ++w) {
                float f000 = wp[w * 5 + 0];
                float f110 = wp[w * 5 + 1];
                float f112 = wp[w * 5 + 2];
                float fuv  = wp[w * 5 + 3];
                float fvu  = wp[w * 5 + 4];
                acc0[w] += f000 * s0p + f110 * s1p;
                acc1[w][0] += fuv * p0 + fvu * q0;
                acc1[w][1] += fuv * p1 + fvu * q1;
                acc1[w][2] += fuv * p2 + fvu * q2;
                acc2[w][0] += f112 * t0;
                acc2[w][1] += f112 * t1;
                acc2[w][2] += f112 * t2;
                acc2[w][3] += f112 * t3;
                acc2[w][4] += f112 * t4;
            }
            wp += 80;
        }
    }

    // write 144 floats per node as 36 float4 stores
    float4* o4 = (float4*)(out + (blockNode + tid) * 144);
#pragma unroll
    for (int j = 0; j < 4; ++j) {
        o4[j] = make_float4(acc0[4 * j], acc0[4 * j + 1],
                            acc0[4 * j + 2], acc0[4 * j + 3]);
    }
#pragma unroll
    for (int j = 0; j < 12; ++j) {
        int e = 4 * j;
        o4[4 + j] = make_float4(acc1[(e + 0) / 3][(e + 0) % 3],
                                acc1[(e + 1) / 3][(e + 1) % 3],
                                acc1[(e + 2) / 3][(e + 2) % 3],
                                acc1[(e + 3) / 3][(e + 3) % 3]);
    }
#pragma unroll
    for (int j = 0; j < 20; ++j) {
        int e = 4 * j;
        o4[16 + j] = make_float4(acc2[(e + 0) / 5][(e + 0) % 5],
                                 acc2[(e + 1) / 5][(e + 1) % 5],
                                 acc2[(e + 2) / 5][(e + 2) % 5],
                                 acc2[(e + 3) / 5][(e + 3) % 5]);
    }
}

extern "C" void kernel_launch(void* const* d_in, const int* in_sizes, int n_in,
                              void* d_out, int out_size, void* d_ws, size_t ws_size,
                              hipStream_t stream) {
    const float* feats = (const float*)d_in[0];
    const float* msgs  = (const float*)d_in[1];
    const float* w000  = (const float*)d_in[2];
    const float* w101  = (const float*)d_in[3];
    const float* w110  = (const float*)d_in[4];
    const float* w112  = (const float*)d_in[5];
    float* ws  = (float*)d_ws;
    float* out = (float*)d_out;

    const int n = in_sizes[0] / (4 * MUL);   // number of nodes (131072)

    prep_weights<<<(NPAIR * MUL + 255) / 256, 256, 0, stream>>>(w000, w101, w110, w112, ws);
    tsq_kernel<<<n / 256, 256, 0, stream>>>(feats, msgs, ws, out);
}